// Round 1
// baseline (8472.753 us; speedup 1.0000x reference)
//
#include <hip/hip_runtime.h>

#define N 8192
#define MAX_ITER 128
#define EPS 1e-6f
#define TAU_I8 12.0f     // int8 screen band: quant sigma ~1.63 -> 7.3 sigma
#define TAU_R  0.05f     // residual tier band: sigma ~6.4e-3 -> 7.8 sigma
#define QINV   0.0625f   // 1/16
#define RINV   (1.0f/4096.0f)
#define GRP    64        // column groups in accum
#define SEGS   32        // row segments in accum (256 rows each)

#if defined(__has_builtin)
#  if __has_builtin(__builtin_amdgcn_sdot4)
#    define SDOT4(a,b,c) __builtin_amdgcn_sdot4((a),(b),(c),false)
#  endif
#endif
#ifndef SDOT4
static __device__ __forceinline__ int sdot4_sw(int a, int b, int c) {
    c += (int)(signed char)(a & 0xff)       * (int)(signed char)(b & 0xff);
    c += (int)(signed char)((a>>8) & 0xff)  * (int)(signed char)((b>>8) & 0xff);
    c += (int)(signed char)((a>>16) & 0xff) * (int)(signed char)((b>>16) & 0xff);
    c += (int)(signed char)((a>>24) & 0xff) * (int)(signed char)((b>>24) & 0xff);
    return c;
}
#define SDOT4(a,b,c) sdot4_sw((a),(b),(c))
#endif

// ---------------------------------------------------------------------------
__global__ __launch_bounds__(256) void init_kernel(int* __restrict__ yint,
                                                   int* __restrict__ satflag,
                                                   int* __restrict__ cnt,
                                                   int* __restrict__ done) {
    const int i = blockIdx.x * 256 + threadIdx.x;
    yint[i] = 0;
    satflag[i] = 0;
    if (i == 0) { cnt[0] = 0; cnt[1] = 0; *done = 0; }
}

// ---------------------------------------------------------------------------
// compressT: W fp32 -> WqT int8 (transposed, scale 16) + Rq int8 residual
// (row-major, scale 4096). Quantization math identical to the validated
// compress_kernel so all tier values are bit-identical.
// 64x64 tiles, LDS transpose for the WqT write.
// ---------------------------------------------------------------------------
__global__ __launch_bounds__(256)
void compressT_kernel(const float* __restrict__ W,
                      signed char* __restrict__ WqT,
                      signed char* __restrict__ Rq,
                      int* __restrict__ satflag) {
    __shared__ unsigned tq[64][17];          // [row in tile][uint col], padded
    const int bid = blockIdx.x;
    const int ti = bid >> 7, tj = bid & 127; // 128x128 tiles of 64x64
    const int i0 = ti << 6, j0 = tj << 6;
    const int tid = threadIdx.x;
    const int r  = tid >> 2, q4 = tid & 3;   // row in tile, 16-col quarter
    const float4* wrow = (const float4*)(W + (size_t)(i0 + r) * N + j0 + (q4 << 4));
    int sat = 0;
    uint4 orr;
    unsigned* pr = (unsigned*)&orr;
    #pragma unroll
    for (int v = 0; v < 4; ++v) {
        float4 w = wrow[v];
        unsigned uq = 0, ur = 0;
        const float* e = (const float*)&w;
        #pragma unroll
        for (int k = 0; k < 4; ++k) {
            int q = __float2int_rn(e[k] * 16.0f);
            if (q > 127)  { q = 127;  sat = 1; }
            if (q < -127) { q = -127; sat = 1; }
            float rr = e[k] - (float)q * QINV;       // exact (same binade)
            int rq = __float2int_rn(rr * 4096.0f);
            if (rq > 127)  rq = 127;
            if (rq < -127) rq = -127;
            uq |= ((unsigned)(q & 0xff)) << (8 * k);
            ur |= ((unsigned)(rq & 0xff)) << (8 * k);
        }
        pr[v] = ur;
        tq[r][(q4 << 2) + v] = uq;
    }
    *(uint4*)(Rq + (size_t)(i0 + r) * N + j0 + (q4 << 4)) = orr;
    if (sat) atomicOr(&satflag[i0 + r], 1);
    __syncthreads();
    // transposed write: thread -> col c, 16-row quarter qq
    const int c = tid >> 2, qq = tid & 3;
    unsigned ob[4];
    #pragma unroll
    for (int v = 0; v < 4; ++v) {
        const int rb = (qq << 4) + (v << 2);
        const unsigned b0 = (tq[rb + 0][c >> 2] >> ((c & 3) * 8)) & 0xff;
        const unsigned b1 = (tq[rb + 1][c >> 2] >> ((c & 3) * 8)) & 0xff;
        const unsigned b2 = (tq[rb + 2][c >> 2] >> ((c & 3) * 8)) & 0xff;
        const unsigned b3 = (tq[rb + 3][c >> 2] >> ((c & 3) * 8)) & 0xff;
        ob[v] = b0 | (b1 << 8) | (b2 << 16) | (b3 << 24);
    }
    *(uint4*)(WqT + (size_t)(j0 + c) * N + i0 + (qq << 4)) = *(uint4*)ob;
}

// ---------------------------------------------------------------------------
// t0: exact fp32 matvec y0 = W@x0 (validated R3 accumulation order).
// Writes packed x_1. Energy machinery removed (convergence is now flip-based).
// ---------------------------------------------------------------------------
__global__ __launch_bounds__(512, 4)
void t0_kernel(const float* __restrict__ W,
               const float* __restrict__ bias,
               const float* __restrict__ x0,
               signed char* __restrict__ xout) {      // packed x_1
    __shared__ float xs[N];
    const int tid = threadIdx.x;
    {
        const float4* x4 = (const float4*)x0;
        float4* s4 = (float4*)xs;
        for (int i = tid; i < N / 4; i += 512) s4[i] = x4[i];
    }
    __syncthreads();
    const int wave = tid >> 6;
    const int lane = tid & 63;
    const int row  = ((int)blockIdx.x << 3) + wave;
    const float4* Wr  = (const float4*)(W + (size_t)row * N);
    const float4* xs4 = (const float4*)xs;
    float a0 = 0.f, a1 = 0.f, a2 = 0.f, a3 = 0.f;
    #pragma unroll
    for (int p = 0; p < 8; ++p) {                    // EXACT R3 inner body
        int j = p * 256 + lane;
        float4 w0 = Wr[j];         float4 q0 = xs4[j];
        float4 w1 = Wr[j + 64];    float4 q1 = xs4[j + 64];
        float4 w2 = Wr[j + 128];   float4 q2 = xs4[j + 128];
        float4 w3 = Wr[j + 192];   float4 q3 = xs4[j + 192];
        a0 += w0.x * q0.x + w0.y * q0.y + w0.z * q0.z + w0.w * q0.w;
        a1 += w1.x * q1.x + w1.y * q1.y + w1.z * q1.z + w1.w * q1.w;
        a2 += w2.x * q2.x + w2.y * q2.y + w2.z * q2.z + w2.w * q2.w;
        a3 += w3.x * q3.x + w3.y * q3.y + w3.z * q3.z + w3.w * q3.w;
    }
    float tot = (a0 + a1) + (a2 + a3);
    #pragma unroll
    for (int off = 32; off > 0; off >>= 1) tot += __shfl_down(tot, off);
    if (lane == 0) {
        const float v = tot + bias[row];
        xout[row] = (signed char)((v > 0.f) ? 1 : ((v < 0.f) ? -1 : 0));
    }
}

// ---------------------------------------------------------------------------
// accum(t): incremental y update. Grid = GRP(64) col-groups x SEGS(32)
// row-segments (256 rows each) = 2048 blocks x 256 thr. Each wave reads one
// column's 256-byte segment per iteration (contiguous, 64 lanes x 4B).
// dense=1 (t=1): all 8192 columns, delta = x_1[j] (y from 0).
// dense=0 (t>=2): columns from the flip list, delta in {-2..2}.
// Integer adds are exact and order-independent -> deterministic result.
// ---------------------------------------------------------------------------
__global__ __launch_bounds__(256, 8)
void accum_kernel(const signed char* __restrict__ WqT,
                  const signed char* __restrict__ xcur,   // packed x_t (dense)
                  const int* __restrict__ list,           // flip entries
                  const int* __restrict__ count,
                  int* __restrict__ nextcount,            // zeroed here
                  int* __restrict__ ypart,                // [GRP][N]
                  const int* __restrict__ done,
                  int dense) {
    if (*done) return;
    const int tid = threadIdx.x;
    if (blockIdx.x == 0 && tid == 0) *nextcount = 0;
    const int g = blockIdx.x >> 5;        // 0..63 column group
    const int s = blockIdx.x & 31;        // 0..31 row segment
    const int seg0 = s << 8;              // 256 rows per segment
    const int wave = tid >> 6, lane = tid & 63;
    __shared__ int elist[128];
    __shared__ int red[4][256];
    int nc;
    if (dense) {
        nc = 128;                         // 64 groups x 128 cols = 8192
    } else {
        const int k = *count;
        const int cpg = (k + 63) >> 6;
        const int beg = g * cpg;
        nc = k - beg; if (nc < 0) nc = 0; if (nc > cpg) nc = cpg;
        for (int e = tid; e < nc; e += 256) elist[e] = list[beg + e];
    }
    __syncthreads();
    int a0 = 0, a1 = 0, a2 = 0, a3 = 0;
    if (dense) {
        for (int e = wave; e < nc; e += 4) {
            const int j = (g << 7) + e;
            const int d = (int)xcur[j];                     // wave-uniform
            const unsigned w = *(const unsigned*)(WqT + (size_t)j * N + seg0 + (lane << 2));
            a0 += d * (int)(signed char)(w & 0xff);
            a1 += d * (int)(signed char)((w >> 8) & 0xff);
            a2 += d * (int)(signed char)((w >> 16) & 0xff);
            a3 += d * (int)(signed char)(w >> 24);
        }
    } else {
        for (int e = wave; e < nc; e += 4) {
            const int en = elist[e];                        // LDS broadcast
            const int j = en >> 3;
            const int d = (en & 7) - 2;
            const unsigned w = *(const unsigned*)(WqT + (size_t)j * N + seg0 + (lane << 2));
            a0 += d * (int)(signed char)(w & 0xff);
            a1 += d * (int)(signed char)((w >> 8) & 0xff);
            a2 += d * (int)(signed char)((w >> 16) & 0xff);
            a3 += d * (int)(signed char)(w >> 24);
        }
    }
    *(int4*)&red[wave][lane << 2] = make_int4(a0, a1, a2, a3);
    __syncthreads();
    const int v = (red[0][tid] + red[1][tid]) + (red[2][tid] + red[3][tid]);
    ypart[(g << 13) + seg0 + tid] = v;
}

// ---------------------------------------------------------------------------
// decide(t): 2048 blocks x 256 thr, 1 row/wave. Sums the 64 group partials,
// updates persistent y_int (exact int32 of Wq@x_t), runs the unchanged tier
// ladder (Rq residual screen, exact fp32 R3-order fallback), writes packed
// x_{t+1} and appends flips for the next accum. Convergence: flip count 0
// <=> x_t == x_{t-1} <=> the reference's |dE|<1e-6 fixed-point trigger.
// ---------------------------------------------------------------------------
__global__ __launch_bounds__(256, 8)
void decide_kernel(const signed char* __restrict__ Rq,
                   const float* __restrict__ W,
                   const float* __restrict__ bias,
                   const signed char* __restrict__ xin,   // packed x_t
                   signed char* __restrict__ xout,        // packed x_{t+1}
                   const int* __restrict__ ypart,
                   int* __restrict__ yint,
                   const int* __restrict__ count,         // flips x_{t-1}->x_t
                   int* __restrict__ nlist,
                   int* __restrict__ ncount,
                   const int* __restrict__ satflag,
                   int t,
                   int* __restrict__ done) {
    if (*done) return;                       // uniform
    if (t >= 2 && *count == 0) {             // x_t == x_{t-1}: fixed point
        if (blockIdx.x == 0 && threadIdx.x == 0) *done = 1 + (t & 1);
        return;                              // final = x_t, frozen
    }
    const int tid  = threadIdx.x;
    const int wave = tid >> 6;
    const int lane = tid & 63;
    const int row  = ((int)blockIdx.x << 2) + wave;

    // y = yint + sum over 64 group partials (exact int32)
    int yp = ypart[(lane << 13) + row];
    #pragma unroll
    for (int off = 32; off > 0; off >>= 1) yp += __shfl_xor(yp, off);
    const int acc = yint[row] + yp;          // wave-uniform after reduce
    if (lane == 0) yint[row] = acc;

    const float br  = bias[row];
    const int   sat = satflag[row];
    float yfin = (float)acc * QINV;

    const uint4* xs4 = (const uint4*)xin;
    if (fabsf(yfin + br) < TAU_I8 || sat) {
        // ---- residual tier: 8 KB Rq row, exact int32 ----
        const uint4* Rr = (const uint4*)(Rq + (size_t)row * N);
        int racc = 0;
        #pragma unroll
        for (int p = 0; p < 8; ++p) {
            const uint4 xv = xs4[(p << 6) + lane];
            const uint4 w  = Rr[(p << 6) + lane];
            racc = SDOT4((int)w.x, (int)xv.x, racc);
            racc = SDOT4((int)w.y, (int)xv.y, racc);
            racc = SDOT4((int)w.z, (int)xv.z, racc);
            racc = SDOT4((int)w.w, (int)xv.w, racc);
        }
        #pragma unroll
        for (int off = 1; off < 64; off <<= 1) racc += __shfl_xor(racc, off);
        yfin = (float)acc * QINV + (float)racc * RINV;

        if (fabsf(yfin + br) < TAU_R || sat) {
            // ---- exact fp32, bitwise-identical to validated R3 order ----
            const float4* Wf = (const float4*)(W + (size_t)row * N);
            const unsigned* xw = (const unsigned*)xin;
            float b0 = 0.f, b1 = 0.f, b2 = 0.f, b3 = 0.f;
            #pragma unroll
            for (int p = 0; p < 8; ++p) {
                const int j = p * 256 + lane;
                #pragma unroll
                for (int c = 0; c < 4; ++c) {
                    const int idx = j + c * 64;
                    const float4 w = Wf[idx];
                    const unsigned u = xw[idx];      // elements 4idx..4idx+3
                    float4 q;
                    q.x = (float)(signed char)(u & 0xff);
                    q.y = (float)(signed char)((u >> 8) & 0xff);
                    q.z = (float)(signed char)((u >> 16) & 0xff);
                    q.w = (float)(signed char)(u >> 24);
                    const float d = w.x * q.x + w.y * q.y + w.z * q.z + w.w * q.w;
                    if (c == 0) b0 += d; else if (c == 1) b1 += d;
                    else if (c == 2) b2 += d; else b3 += d;
                }
            }
            float tot = (b0 + b1) + (b2 + b3);
            #pragma unroll
            for (int off = 32; off > 0; off >>= 1) tot += __shfl_down(tot, off);
            yfin = tot;                      // valid on lane 0 (the writer)
        }
    }

    if (lane == 0) {
        const float v = yfin + br;
        const signed char nv = (signed char)((v > 0.f) ? 1 : ((v < 0.f) ? -1 : 0));
        xout[row] = nv;
        const signed char ov = xin[row];
        if (nv != ov) {
            const int d = (int)nv - (int)ov;             // in {-2,-1,1,2}
            const int idx = atomicAdd(ncount, 1);
            nlist[idx] = (row << 3) | ((d + 2) & 7);
        }
    }
}

// ---------------------------------------------------------------------------
// out: decode the final buffer. No done -> x_128 (xpk0). done encodes parity.
// ---------------------------------------------------------------------------
__global__ __launch_bounds__(256)
void out_kernel(const signed char* __restrict__ xpk0,
                const signed char* __restrict__ xpk1,
                const int* __restrict__ done,
                float* __restrict__ out) {
    const int d = *done;
    const signed char* xf = d ? ((d - 1) ? xpk1 : xpk0) : xpk0;
    const int i = blockIdx.x * 256 + threadIdx.x;
    const char4 c = ((const char4*)xf)[i];
    ((float4*)out)[i] = make_float4((float)c.x, (float)c.y, (float)c.z, (float)c.w);
}

// ===========================================================================
// Fallback (ws too small): the validated R3 full-fp32 chain.
// ===========================================================================
__global__ __launch_bounds__(256) void fb_init(float* __restrict__ eacc,
                                               int* __restrict__ done) {
    int i = threadIdx.x;
    if (i <= MAX_ITER) eacc[i] = 0.0f;
    if (i == 0) *done = 0;
}

__global__ __launch_bounds__(512, 4) void fb_mv(const float* __restrict__ W,
                                                const float* __restrict__ bias,
                                                const float* __restrict__ x0,
                                                const signed char* __restrict__ xin,
                                                signed char* __restrict__ xnext,
                                                float* __restrict__ eacc,
                                                int t,
                                                int* __restrict__ done) {
    if (t >= 2) {
        if (*done) return;
        float d = fabsf(eacc[t - 1] - eacc[t - 2]);
        if (d < EPS) {
            if (threadIdx.x == 0) *done = 1 + ((t - 1) & 1);
            return;
        }
    }
    __shared__ float xs[N];
    __shared__ float wsum[8];
    if (t == 0) {
        const float4* x4 = (const float4*)x0;
        float4* s4 = (float4*)xs;
        for (int i = threadIdx.x; i < N / 4; i += 512) s4[i] = x4[i];
    } else {
        #pragma unroll
        for (int k = 0; k < 16; ++k) {
            int e = threadIdx.x + k * 512;
            xs[e] = (float)xin[e];
        }
    }
    __syncthreads();
    const int wave = threadIdx.x >> 6;
    const int lane = threadIdx.x & 63;
    const int row  = ((int)blockIdx.x << 3) + wave;
    const float4* Wr  = (const float4*)(W + (size_t)row * N);
    const float4* xs4 = (const float4*)xs;
    float a0 = 0.f, a1 = 0.f, a2 = 0.f, a3 = 0.f;
    #pragma unroll
    for (int p = 0; p < 8; ++p) {
        int j = p * 256 + lane;
        float4 w0 = Wr[j];         float4 q0 = xs4[j];
        float4 w1 = Wr[j + 64];    float4 q1 = xs4[j + 64];
        float4 w2 = Wr[j + 128];   float4 q2 = xs4[j + 128];
        float4 w3 = Wr[j + 192];   float4 q3 = xs4[j + 192];
        a0 += w0.x * q0.x + w0.y * q0.y + w0.z * q0.z + w0.w * q0.w;
        a1 += w1.x * q1.x + w1.y * q1.y + w1.z * q1.z + w1.w * q1.w;
        a2 += w2.x * q2.x + w2.y * q2.y + w2.z * q2.z + w2.w * q2.w;
        a3 += w3.x * q3.x + w3.y * q3.y + w3.z * q3.z + w3.w * q3.w;
    }
    float tot = (a0 + a1) + (a2 + a3);
    #pragma unroll
    for (int off = 32; off > 0; off >>= 1) tot += __shfl_down(tot, off);
    if (lane == 0) {
        float br = bias[row];
        float v = tot + br;
        xnext[row] = (signed char)((v > 0.f) ? 1 : ((v < 0.f) ? -1 : 0));
        float xr = xs[row];
        wsum[wave] = -0.5f * xr * tot - br * xr;
    }
    __syncthreads();
    if (threadIdx.x == 0) {
        float s = 0.f;
        #pragma unroll
        for (int w = 0; w < 8; ++w) s += wsum[w];
        atomicAdd(&eacc[t], s);
    }
}

__global__ __launch_bounds__(256) void fb_out(const signed char* __restrict__ p0,
                                              const signed char* __restrict__ p1,
                                              const int* __restrict__ done,
                                              float* __restrict__ out) {
    int i = blockIdx.x * 256 + threadIdx.x;
    int d = *done;
    const signed char* p = d ? ((d - 1) ? p1 : p0) : p0;
    out[i] = (float)p[i];
}

// ===========================================================================
extern "C" void kernel_launch(void* const* d_in, const int* in_sizes, int n_in,
                              void* d_out, int out_size, void* d_ws, size_t ws_size,
                              hipStream_t stream) {
    const float* x0 = (const float*)d_in[0];   // (8192,)
    const float* W  = (const float*)d_in[1];   // (8192, 8192) fp32
    const float* b  = (const float*)d_in[2];   // (8192,)
    float* out = (float*)d_out;

    // fast-path workspace layout (16B-aligned pieces)
    char* p = (char*)d_ws;
    signed char* WqT = (signed char*)p;       p += (size_t)N * N;          // 64 MiB
    signed char* Rq  = (signed char*)p;       p += (size_t)N * N;          // 64 MiB
    signed char* xpk0 = (signed char*)p;      p += N;                      // packed x (even)
    signed char* xpk1 = (signed char*)p;      p += N;                      // packed x (odd)
    int* yint = (int*)p;                      p += N * sizeof(int);        // persistent y
    int* ypart = (int*)p;                     p += (size_t)GRP * N * sizeof(int); // 2 MiB
    int* list0 = (int*)p;                     p += N * sizeof(int);
    int* list1 = (int*)p;                     p += N * sizeof(int);
    int* satflag = (int*)p;                   p += N * sizeof(int);
    int* cnt = (int*)p;                       p += 16;
    int* done = (int*)p;                      p += 16;
    const size_t needed = (size_t)(p - (char*)d_ws);

    if (ws_size >= needed) {
        init_kernel<<<N / 256, 256, 0, stream>>>(yint, satflag, cnt, done);
        compressT_kernel<<<(N / 64) * (N / 64), 256, 0, stream>>>(W, WqT, Rq, satflag);
        // t=0: exact fp32, writes x_1 -> xpk1
        t0_kernel<<<N / 8, 512, 0, stream>>>(W, b, x0, xpk1);
        // t=1: dense column pass builds y_int = Wq @ x_1, decides x_2 -> xpk0
        accum_kernel<<<GRP * SEGS, 256, 0, stream>>>(WqT, xpk1, list0, cnt + 1,
                                                     cnt + 0, ypart, done, 1);
        decide_kernel<<<N / 4, 256, 0, stream>>>(Rq, W, b, xpk1, xpk0, ypart, yint,
                                                 cnt + 1, list0, cnt + 0, satflag,
                                                 1, done);
        for (int t = 2; t < MAX_ITER; ++t) {
            const int cur = t & 1;
            const signed char* xin = cur ? xpk1 : xpk0;   // x_t
            signed char* xo        = cur ? xpk0 : xpk1;   // x_{t+1}
            int* lcur = cur ? list1 : list0;              // flips x_{t-1}->x_t
            int* lnxt = cur ? list0 : list1;              // flips x_t->x_{t+1}
            accum_kernel<<<GRP * SEGS, 256, 0, stream>>>(WqT, xin, lcur, cnt + cur,
                                                         cnt + (cur ^ 1), ypart,
                                                         done, 0);
            decide_kernel<<<N / 4, 256, 0, stream>>>(Rq, W, b, xin, xo, ypart, yint,
                                                     cnt + cur, lnxt, cnt + (cur ^ 1),
                                                     satflag, t, done);
        }
        out_kernel<<<N / 4 / 256, 256, 0, stream>>>(xpk0, xpk1, done, out);
    } else {
        // fallback: validated R3 chain
        float*       feacc = (float*)d_ws;
        int*         fdone = (int*)(feacc + MAX_ITER + 2);
        signed char* p0    = (signed char*)(fdone + 16);
        signed char* p1    = p0 + N;
        fb_init<<<1, 256, 0, stream>>>(feacc, fdone);
        for (int t = 0; t <= MAX_ITER; ++t) {
            const signed char* xin   = (t & 1) ? p1 : p0;
            signed char*       xnext = (t & 1) ? p0 : p1;
            fb_mv<<<N / 8, 512, 0, stream>>>(W, b, x0, xin, xnext, feacc, t, fdone);
        }
        fb_out<<<N / 256, 256, 0, stream>>>(p0, p1, fdone, out);
    }
}

// Round 6
// 4283.152 us; speedup vs baseline: 1.9782x; 1.9782x over previous
//
#include <hip/hip_runtime.h>

#define N 8192
#define MAX_ITER 128
#define EPS 1e-6f
#define TAU_I8 12.0f     // int8 screen band: quant sigma ~1.63 -> 7.3 sigma
#define TAU_R  0.05f     // residual tier band: sigma ~6.4e-3 -> 7.8 sigma
#define QINV   0.0625f   // 1/16
#define RINV   (1.0f/4096.0f)

#if defined(__has_builtin)
#  if __has_builtin(__builtin_amdgcn_sdot4)
#    define SDOT4(a,b,c) __builtin_amdgcn_sdot4((a),(b),(c),false)
#  endif
#endif
#ifndef SDOT4
static __device__ __forceinline__ int sdot4_sw(int a, int b, int c) {
    c += (int)(signed char)(a & 0xff)       * (int)(signed char)(b & 0xff);
    c += (int)(signed char)((a>>8) & 0xff)  * (int)(signed char)((b>>8) & 0xff);
    c += (int)(signed char)((a>>16) & 0xff) * (int)(signed char)((b>>16) & 0xff);
    c += (int)(signed char)((a>>24) & 0xff) * (int)(signed char)((b>>24) & 0xff);
    return c;
}
#define SDOT4(a,b,c) sdot4_sw((a),(b),(c))
#endif

// ---------------------------------------------------------------------------
__global__ __launch_bounds__(256) void init_kernel(int* __restrict__ cnt,
                                                   int* __restrict__ cnt2,
                                                   int* __restrict__ satflag,
                                                   int* __restrict__ done) {
    const int i = blockIdx.x * 256 + threadIdx.x;
    if (i < N) satflag[i] = 0;
    if (i < MAX_ITER) { cnt[i] = 0; cnt2[i] = 0; }
    if (i == 0) *done = 0;
}

// ---------------------------------------------------------------------------
// compress: W fp32 -> Wq int8 (row-major, scale 16) + Rq int8 residual
// (row-major, scale 4096). Bit-identical to the validated R0 quantization.
// ---------------------------------------------------------------------------
__global__ __launch_bounds__(256) void compress_kernel(const float* __restrict__ W,
                                                       signed char* __restrict__ Wq,
                                                       signed char* __restrict__ Rq,
                                                       int* __restrict__ satflag) {
    const size_t base = ((size_t)blockIdx.x * 256 + threadIdx.x) * 16;
    const float4* w4 = (const float4*)(W + base);
    int sat = 0;
    uint4 oq, orr;
    unsigned* pq = (unsigned*)&oq;
    unsigned* pr = (unsigned*)&orr;
    #pragma unroll
    for (int v = 0; v < 4; ++v) {
        float4 w = w4[v];
        unsigned uq = 0, ur = 0;
        const float* e = (const float*)&w;
        #pragma unroll
        for (int k = 0; k < 4; ++k) {
            int q = __float2int_rn(e[k] * 16.0f);
            if (q > 127)  { q = 127;  sat = 1; }
            if (q < -127) { q = -127; sat = 1; }
            float r = e[k] - (float)q * QINV;        // exact (same binade)
            int rq = __float2int_rn(r * 4096.0f);
            if (rq > 127)  rq = 127;
            if (rq < -127) rq = -127;
            uq |= ((unsigned)(q & 0xff)) << (8 * k);
            ur |= ((unsigned)(rq & 0xff)) << (8 * k);
        }
        pq[v] = uq; pr[v] = ur;
    }
    *(uint4*)(Wq + base) = oq;
    *(uint4*)(Rq + base) = orr;
    if (sat) atomicOr(&satflag[base >> 13], 1);
}

// ---------------------------------------------------------------------------
// t0: exact fp32 matvec y0 = W@x0 (validated R3 accumulation order).
// Writes packed x_1. No energy machinery (convergence is flip-based).
// ---------------------------------------------------------------------------
__global__ __launch_bounds__(512, 4)
void t0_kernel(const float* __restrict__ W,
               const float* __restrict__ bias,
               const float* __restrict__ x0,
               signed char* __restrict__ xout) {      // packed x_1
    __shared__ float xs[N];
    const int tid = threadIdx.x;
    {
        const float4* x4 = (const float4*)x0;
        float4* s4 = (float4*)xs;
        for (int i = tid; i < N / 4; i += 512) s4[i] = x4[i];
    }
    __syncthreads();
    const int wave = tid >> 6;
    const int lane = tid & 63;
    const int row  = ((int)blockIdx.x << 3) + wave;
    const float4* Wr  = (const float4*)(W + (size_t)row * N);
    const float4* xs4 = (const float4*)xs;
    float a0 = 0.f, a1 = 0.f, a2 = 0.f, a3 = 0.f;
    #pragma unroll
    for (int p = 0; p < 8; ++p) {                    // EXACT R3 inner body
        int j = p * 256 + lane;
        float4 w0 = Wr[j];         float4 q0 = xs4[j];
        float4 w1 = Wr[j + 64];    float4 q1 = xs4[j + 64];
        float4 w2 = Wr[j + 128];   float4 q2 = xs4[j + 128];
        float4 w3 = Wr[j + 192];   float4 q3 = xs4[j + 192];
        a0 += w0.x * q0.x + w0.y * q0.y + w0.z * q0.z + w0.w * q0.w;
        a1 += w1.x * q1.x + w1.y * q1.y + w1.z * q1.z + w1.w * q1.w;
        a2 += w2.x * q2.x + w2.y * q2.y + w2.z * q2.z + w2.w * q2.w;
        a3 += w3.x * q3.x + w3.y * q3.y + w3.z * q3.z + w3.w * q3.w;
    }
    float tot = (a0 + a1) + (a2 + a3);
    #pragma unroll
    for (int off = 32; off > 0; off >>= 1) tot += __shfl_down(tot, off);
    if (lane == 0) {
        const float v = tot + bias[row];
        xout[row] = (signed char)((v > 0.f) ? 1 : ((v < 0.f) ? -1 : 0));
    }
}

// ---------------------------------------------------------------------------
// step(t), t=1..127: 2048 blocks x 256 thr (4 waves, 1 row/wave).
// __launch_bounds__(256,4): VGPR cap 128 (NOT 64) -> no scratch spills; the
// 8-uint4 Wq preload stays resident across the x-staging barrier.
// Convergence: cnt[t-1]==0  <=> x_t == x_{t-1}  (fixed point, final = x_t).
// Cycle skip:  cnt2[t-1]==0 <=> x_t == x_{t-2}  (period-2 orbit; trajectory
// is exactly deterministic from here, x_128 is the even-parity element which
// by buffer parity always sits in xpk0 -> done=1).
// ---------------------------------------------------------------------------
__global__ __launch_bounds__(256, 4)
void step_kernel(const signed char* __restrict__ Wq,
                 const signed char* __restrict__ Rq,
                 const float* __restrict__ W,
                 const float* __restrict__ bias,
                 const signed char* __restrict__ xin,    // packed x_t
                 signed char* __restrict__ xout,         // holds x_{t-1}; gets x_{t+1}
                 int* __restrict__ cnt,                  // cnt[s] = flips(x_{s+1},x_s)
                 int* __restrict__ cnt2,                 // cnt2[s]= flips(x_{s+1},x_{s-1})
                 const int* __restrict__ satflag,
                 int t,
                 int* __restrict__ done) {
    if (*done) return;                       // uniform
    if (t >= 2 && cnt[t - 1] == 0) {         // x_t == x_{t-1}: fixed point
        if (blockIdx.x == 0 && threadIdx.x == 0) *done = 1 + (t & 1);
        return;                              // final = x_t, frozen
    }
    if (t >= 3 && cnt2[t - 1] == 0) {        // x_t == x_{t-2}: exact 2-cycle
        if (blockIdx.x == 0 && threadIdx.x == 0) *done = 1;
        return;                              // x_128 (even) lives in xpk0
    }

    __shared__ unsigned xq[2048];            // 8 KB packed x_t
    __shared__ int fcnt[2];

    const int tid  = threadIdx.x;
    const int wave = tid >> 6;
    const int lane = tid & 63;
    const int row  = ((int)blockIdx.x << 2) + wave;

    // preload int8 W row (overlaps the staging barrier)
    const uint4* Wr = (const uint4*)(Wq + (size_t)row * N);
    uint4 wq[8];
    #pragma unroll
    for (int p = 0; p < 8; ++p) wq[p] = Wr[(p << 6) + lane];

    // stage packed x_t
    {
        const uint4* xg4 = (const uint4*)xin;
        uint4* xs4w = (uint4*)xq;
        xs4w[tid]       = xg4[tid];
        xs4w[tid + 256] = xg4[tid + 256];
    }
    if (tid < 2) fcnt[tid] = 0;
    __syncthreads();

    // ---- sdot4 screen: exact int32, order-independent ----
    const uint4* xs4 = (const uint4*)xq;
    int acc = 0;
    #pragma unroll
    for (int p = 0; p < 8; ++p) {
        const uint4 xv = xs4[(p << 6) + lane];
        const uint4 w  = wq[p];
        acc = SDOT4((int)w.x, (int)xv.x, acc);
        acc = SDOT4((int)w.y, (int)xv.y, acc);
        acc = SDOT4((int)w.z, (int)xv.z, acc);
        acc = SDOT4((int)w.w, (int)xv.w, acc);
    }
    #pragma unroll
    for (int off = 1; off < 64; off <<= 1) acc += __shfl_xor(acc, off);
    // all lanes hold acc -> wave-uniform tier branching

    const float br  = bias[row];             // wave-uniform broadcast load
    const int   sat = satflag[row];
    float yfin = (float)acc * QINV;

    if (fabsf(yfin + br) < TAU_I8 || sat) {
        // ---- residual tier: 8 KB Rq row, exact int32 ----
        const uint4* Rr = (const uint4*)(Rq + (size_t)row * N);
        int racc = 0;
        #pragma unroll
        for (int p = 0; p < 8; ++p) {
            const uint4 xv = xs4[(p << 6) + lane];
            const uint4 w  = Rr[(p << 6) + lane];
            racc = SDOT4((int)w.x, (int)xv.x, racc);
            racc = SDOT4((int)w.y, (int)xv.y, racc);
            racc = SDOT4((int)w.z, (int)xv.z, racc);
            racc = SDOT4((int)w.w, (int)xv.w, racc);
        }
        #pragma unroll
        for (int off = 1; off < 64; off <<= 1) racc += __shfl_xor(racc, off);
        yfin = (float)acc * QINV + (float)racc * RINV;

        if (fabsf(yfin + br) < TAU_R || sat) {
            // ---- exact fp32, bitwise-identical to validated R3 order ----
            const float4* Wf = (const float4*)(W + (size_t)row * N);
            float b0 = 0.f, b1 = 0.f, b2 = 0.f, b3 = 0.f;
            #pragma unroll
            for (int p = 0; p < 8; ++p) {
                const int j = p * 256 + lane;
                #pragma unroll
                for (int c = 0; c < 4; ++c) {
                    const int idx = j + c * 64;
                    const float4 w = Wf[idx];
                    const unsigned u = xq[idx];      // elements 4idx..4idx+3
                    float4 q;
                    q.x = (float)(signed char)(u & 0xff);
                    q.y = (float)(signed char)((u >> 8) & 0xff);
                    q.z = (float)(signed char)((u >> 16) & 0xff);
                    q.w = (float)(signed char)(u >> 24);
                    const float d = w.x * q.x + w.y * q.y + w.z * q.z + w.w * q.w;
                    if (c == 0) b0 += d; else if (c == 1) b1 += d;
                    else if (c == 2) b2 += d; else b3 += d;
                }
            }
            float tot = (b0 + b1) + (b2 + b3);
            #pragma unroll
            for (int off = 32; off > 0; off >>= 1) tot += __shfl_down(tot, off);
            yfin = tot;                      // valid on lane 0 (the writer)
        }
    }

    if (lane == 0) {
        const float v = yfin + br;
        const signed char nv = (signed char)((v > 0.f) ? 1 : ((v < 0.f) ? -1 : 0));
        const signed char ov  =
            (signed char)((xq[row >> 2] >> ((row & 3) * 8)) & 0xff);  // x_t[row]
        const signed char ov2 = xout[row];                            // x_{t-1}[row]
        xout[row] = nv;
        if (nv != ov)  atomicAdd(&fcnt[0], 1);
        if (t >= 2 && nv != ov2) atomicAdd(&fcnt[1], 1);
    }
    __syncthreads();
    if (tid == 0) {
        if (fcnt[0]) atomicAdd(&cnt[t], fcnt[0]);
        if (t >= 2 && fcnt[1]) atomicAdd(&cnt2[t], fcnt[1]);
    }
}

// ---------------------------------------------------------------------------
// out: decode the final buffer. done==0 -> x_128 (xpk0, even parity).
// ---------------------------------------------------------------------------
__global__ __launch_bounds__(256)
void out_kernel(const signed char* __restrict__ xpk0,
                const signed char* __restrict__ xpk1,
                const int* __restrict__ done,
                float* __restrict__ out) {
    const int d = *done;
    const signed char* xf = d ? ((d - 1) ? xpk1 : xpk0) : xpk0;
    const int i = blockIdx.x * 256 + threadIdx.x;
    const char4 c = ((const char4*)xf)[i];
    ((float4*)out)[i] = make_float4((float)c.x, (float)c.y, (float)c.z, (float)c.w);
}

// ===========================================================================
// Fallback (ws too small): the validated R3 full-fp32 chain.
// ===========================================================================
__global__ __launch_bounds__(256) void fb_init(float* __restrict__ eacc,
                                               int* __restrict__ done) {
    int i = threadIdx.x;
    if (i <= MAX_ITER) eacc[i] = 0.0f;
    if (i == 0) *done = 0;
}

__global__ __launch_bounds__(512, 4) void fb_mv(const float* __restrict__ W,
                                                const float* __restrict__ bias,
                                                const float* __restrict__ x0,
                                                const signed char* __restrict__ xin,
                                                signed char* __restrict__ xnext,
                                                float* __restrict__ eacc,
                                                int t,
                                                int* __restrict__ done) {
    if (t >= 2) {
        if (*done) return;
        float d = fabsf(eacc[t - 1] - eacc[t - 2]);
        if (d < EPS) {
            if (threadIdx.x == 0) *done = 1 + ((t - 1) & 1);
            return;
        }
    }
    __shared__ float xs[N];
    __shared__ float wsum[8];
    if (t == 0) {
        const float4* x4 = (const float4*)x0;
        float4* s4 = (float4*)xs;
        for (int i = threadIdx.x; i < N / 4; i += 512) s4[i] = x4[i];
    } else {
        #pragma unroll
        for (int k = 0; k < 16; ++k) {
            int e = threadIdx.x + k * 512;
            xs[e] = (float)xin[e];
        }
    }
    __syncthreads();
    const int wave = threadIdx.x >> 6;
    const int lane = threadIdx.x & 63;
    const int row  = ((int)blockIdx.x << 3) + wave;
    const float4* Wr  = (const float4*)(W + (size_t)row * N);
    const float4* xs4 = (const float4*)xs;
    float a0 = 0.f, a1 = 0.f, a2 = 0.f, a3 = 0.f;
    #pragma unroll
    for (int p = 0; p < 8; ++p) {
        int j = p * 256 + lane;
        float4 w0 = Wr[j];         float4 q0 = xs4[j];
        float4 w1 = Wr[j + 64];    float4 q1 = xs4[j + 64];
        float4 w2 = Wr[j + 128];   float4 q2 = xs4[j + 128];
        float4 w3 = Wr[j + 192];   float4 q3 = xs4[j + 192];
        a0 += w0.x * q0.x + w0.y * q0.y + w0.z * q0.z + w0.w * q0.w;
        a1 += w1.x * q1.x + w1.y * q1.y + w1.z * q1.z + w1.w * q1.w;
        a2 += w2.x * q2.x + w2.y * q2.y + w2.z * q2.z + w2.w * q2.w;
        a3 += w3.x * q3.x + w3.y * q3.y + w3.z * q3.z + w3.w * q3.w;
    }
    float tot = (a0 + a1) + (a2 + a3);
    #pragma unroll
    for (int off = 32; off > 0; off >>= 1) tot += __shfl_down(tot, off);
    if (lane == 0) {
        float br = bias[row];
        float v = tot + br;
        xnext[row] = (signed char)((v > 0.f) ? 1 : ((v < 0.f) ? -1 : 0));
        float xr = xs[row];
        wsum[wave] = -0.5f * xr * tot - br * xr;
    }
    __syncthreads();
    if (threadIdx.x == 0) {
        float s = 0.f;
        #pragma unroll
        for (int w = 0; w < 8; ++w) s += wsum[w];
        atomicAdd(&eacc[t], s);
    }
}

__global__ __launch_bounds__(256) void fb_out(const signed char* __restrict__ p0,
                                              const signed char* __restrict__ p1,
                                              const int* __restrict__ done,
                                              float* __restrict__ out) {
    int i = blockIdx.x * 256 + threadIdx.x;
    int d = *done;
    const signed char* p = d ? ((d - 1) ? p1 : p0) : p0;
    out[i] = (float)p[i];
}

// ===========================================================================
extern "C" void kernel_launch(void* const* d_in, const int* in_sizes, int n_in,
                              void* d_out, int out_size, void* d_ws, size_t ws_size,
                              hipStream_t stream) {
    const float* x0 = (const float*)d_in[0];   // (8192,)
    const float* W  = (const float*)d_in[1];   // (8192, 8192) fp32
    const float* b  = (const float*)d_in[2];   // (8192,)
    float* out = (float*)d_out;

    // fast-path workspace layout (16B-aligned pieces)
    char* p = (char*)d_ws;
    signed char* Wq = (signed char*)p;        p += (size_t)N * N;      // 64 MiB
    signed char* Rq = (signed char*)p;        p += (size_t)N * N;      // 64 MiB
    signed char* xpk0 = (signed char*)p;      p += N;                  // packed x (even)
    signed char* xpk1 = (signed char*)p;      p += N;                  // packed x (odd)
    int* cnt  = (int*)p;                      p += MAX_ITER * sizeof(int);
    int* cnt2 = (int*)p;                      p += MAX_ITER * sizeof(int);
    int* satflag = (int*)p;                   p += N * sizeof(int);
    int* done = (int*)p;                      p += 16;
    const size_t needed = (size_t)(p - (char*)d_ws);

    if (ws_size >= needed) {
        init_kernel<<<N / 256, 256, 0, stream>>>(cnt, cnt2, satflag, done);
        compress_kernel<<<(int)((size_t)N * N / (256 * 16)), 256, 0, stream>>>(W, Wq, Rq, satflag);
        // t=0: exact fp32, writes x_1 -> xpk1 (odd parity)
        t0_kernel<<<N / 8, 512, 0, stream>>>(W, b, x0, xpk1);
        for (int t = 1; t < MAX_ITER; ++t) {
            const int cur = t & 1;
            const signed char* xin = cur ? xpk1 : xpk0;   // x_t
            signed char* xo        = cur ? xpk0 : xpk1;   // x_{t-1} -> x_{t+1}
            step_kernel<<<N / 4, 256, 0, stream>>>(Wq, Rq, W, b, xin, xo,
                                                   cnt, cnt2, satflag, t, done);
        }
        out_kernel<<<N / 4 / 256, 256, 0, stream>>>(xpk0, xpk1, done, out);
    } else {
        // fallback: validated R3 chain
        float*       feacc = (float*)d_ws;
        int*         fdone = (int*)(feacc + MAX_ITER + 2);
        signed char* p0    = (signed char*)(fdone + 16);
        signed char* p1    = p0 + N;
        fb_init<<<1, 256, 0, stream>>>(feacc, fdone);
        for (int t = 0; t <= MAX_ITER; ++t) {
            const signed char* xin   = (t & 1) ? p1 : p0;
            signed char*       xnext = (t & 1) ? p0 : p1;
            fb_mv<<<N / 8, 512, 0, stream>>>(W, b, x0, xin, xnext, feacc, t, fdone);
        }
        fb_out<<<N / 256, 256, 0, stream>>>(p0, p1, fdone, out);
    }
}